// Round 9
// baseline (17020.444 us; speedup 1.0000x reference)
//
#include <hip/hip_runtime.h>

#define BATCH 16
#define NPIX 16384      // B*H*W interior pixels
#define PIXP 20736      // BATCH*36*36 padded pixels
#define TSTEPS 19
#define SPLITWO 4       // split-K chunks for wo conv (3200 -> 4x800)

typedef __attribute__((ext_vector_type(8))) short short8;
typedef __attribute__((ext_vector_type(4))) float f32x4;
typedef __attribute__((ext_vector_type(4))) unsigned int uint4v;
typedef __attribute__((ext_vector_type(2))) unsigned int uint2v;

__device__ __forceinline__ float bf2f(unsigned short u) {
  union { unsigned int i; float f; } v; v.i = ((unsigned int)u) << 16; return v.f;
}
__device__ __forceinline__ unsigned short f2bf(float f) {
  union { float f; unsigned int i; } v; v.f = f;
  unsigned int r = v.i + 0x7FFFu + ((v.i >> 16) & 1u);
  return (unsigned short)(r >> 16);
}
__device__ __forceinline__ float sigm(float x) { return 1.0f / (1.0f + __expf(-x)); }

// K-order is (tap, ci): k = tap*Cin + ci. Activations are channel-last
// [pixel][Cin], so a lane's 8-consecutive-k fragment = one 16B load.
struct Job {
  const unsigned short* W;    // packed [M][Kstride] bf16 (chunk base pre-added)
  const unsigned short* inP;  // padded input, ch-last [PIXP][Cin] bf16
  unsigned short* out;        // ch-last out [NPIX][outStride] bf16
  int outStride;
  int Ktot;                   // local K extent (multiple of 32)
  int Kstride;                // W row stride (elements)
  int kBase;                  // global k offset of this chunk
  int cinShift;               // log2(Cin): 4/6/7
  int yBase;                  // first blockIdx.y tile of this job
  int padAdjPix;              // 0 for 5x5 pad2, 74 for 1x1 pad0 (pixels)
  int Mtot;                   // valid output rows (multiple of 64)
};
struct JobSet { Job jobs[6]; int njobs; };

// ---------------- setup kernels ----------------
__global__ void zero_ws_kernel(uint4v* p, long n16) {
  long i = (long)blockIdx.x * blockDim.x + threadIdx.x;
  long stride = (long)gridDim.x * blockDim.x;
  uint4v z = {0u, 0u, 0u, 0u};
  for (; i < n16; i += stride) p[i] = z;
}

__global__ void cvt_bf16_kernel(const float* __restrict__ s, unsigned short* __restrict__ d, int n) {
  int i = blockIdx.x * 256 + threadIdx.x;
  if (i < n) d[i] = f2bf(s[i]);
}

// repack OIHW f32 [M][cin][25] -> bf16 [M][taps][cin], taps>=25 are zero pad
__global__ void pack_w_kernel(const float* __restrict__ s, unsigned short* __restrict__ d,
                              int M, int taps, int cin) {
  int i = blockIdx.x * 256 + threadIdx.x;
  int per = taps * cin;
  if (i >= M * per) return;
  int m = i / per, r = i - m * per;
  int tap = r / cin, ci = r - tap * cin;
  float v = (tap < 25) ? s[(long)m * (25 * cin) + ci * 25 + tap] : 0.0f;
  d[i] = f2bf(v);
}

// ---------------- conv implicit-GEMM: ch-last direct load, LDS-transpose epi -
// Block 128x128 (Cout x pixels) = 4 waves of 64x64. Per wave-step(K=32):
// 4 A dwordx4 + 4 B dwordx4, 16 MFMA. 2-deep register pipeline, no barriers
// in the K-loop.
__global__ __launch_bounds__(256, 2) void conv_gemm(JobSet js) {
  __shared__ unsigned short eplds[4][64 * 80];   // per-wave transpose tile

  int by = blockIdx.y;
  Job jb = js.jobs[0];
#pragma unroll
  for (int q = 1; q < 6; q++)
    if (q < js.njobs && by >= js.jobs[q].yBase) jb = js.jobs[q];
  int m0 = (by - jb.yBase) * 128;

  int t = threadIdx.x;
  int lane = t & 63;
  int wave = t >> 6;
  int l15 = lane & 15, kg = lane >> 4;
  int wm = (wave >> 1) * 64, wn = (wave & 1) * 64;
  int cin2 = 2 << jb.cinShift;          // bytes per pixel
  int cinMask = (1 << jb.cinShift) - 1;

  // B pixel byte-bases for the 4 n-fragments (padded-corner pixel)
  long nbByte[4];
#pragma unroll
  for (int nf = 0; nf < 4; nf++) {
    int ng = blockIdx.x * 128 + wn + nf * 16 + l15;
    int bb = ng >> 10, rem = ng & 1023;
    int yy = rem >> 5, xx = rem & 31;
    nbByte[nf] = (long)(bb * 1296 + yy * 36 + xx + jb.padAdjPix) * cin2;
  }
  // A element-offsets (row-clamped; epilogue guarded per wave)
  int aoff[4];
#pragma unroll
  for (int mf = 0; mf < 4; mf++) {
    int r = m0 + wm + mf * 16 + l15;
    if (r > jb.Mtot - 1) r = jb.Mtot - 1;
    aoff[mf] = r * jb.Kstride + kg * 8;
  }

  f32x4 acc[4][4];
#pragma unroll
  for (int mf = 0; mf < 4; mf++)
#pragma unroll
    for (int nf = 0; nf < 4; nf++) acc[mf][nf] = (f32x4){0.f, 0.f, 0.f, 0.f};

  const unsigned short* Wp = jb.W;
  const char* ip = (const char*)jb.inP;

  short8 af0[4], bf0[4], af1[4], bf1[4];

  auto loadA = [&](short8* af, int k0) {
#pragma unroll
    for (int mf = 0; mf < 4; mf++)
      af[mf] = *(const short8*)(Wp + aoff[mf] + k0);
  };
  auto loadB = [&](short8* bfv, int k0) {
    int kglob = jb.kBase + k0 + kg * 8;
    int tap = kglob >> jb.cinShift;
    int ci0 = kglob & cinMask;
    int dy = (tap * 13) >> 6;            // tap/5 for tap in [0,25]
    int dx = tap - dy * 5;
    long off = (long)(dy * 36 + dx) * cin2 + ci0 * 2;
#pragma unroll
    for (int nf = 0; nf < 4; nf++)
      bfv[nf] = *(const short8*)(ip + nbByte[nf] + off);
  };
  auto domfma = [&](short8* af, short8* bfv) {
#pragma unroll
    for (int mf = 0; mf < 4; mf++)
#pragma unroll
      for (int nf = 0; nf < 4; nf++)
        acc[mf][nf] = __builtin_amdgcn_mfma_f32_16x16x32_bf16(af[mf], bfv[nf], acc[mf][nf], 0, 0, 0);
  };

  int K = jb.Ktot;
  loadA(af0, 0); loadB(bf0, 0);
  int k0 = 0;
  while (true) {
    int kn = k0 + 32;
    if (kn < K) { loadA(af1, kn); loadB(bf1, kn); }
    domfma(af0, bf0);
    k0 = kn; if (k0 >= K) break;
    kn = k0 + 32;
    if (kn < K) { loadA(af0, kn); loadB(bf0, kn); }
    domfma(af1, bf1);
    k0 = kn; if (k0 >= K) break;
  }

  // epilogue: transpose 64cout x 64pix wave tile via LDS -> ch-last stores.
  // C/D layout: col=lane&15 (pixel), row=(lane>>4)*4+v (cout).
  bool waveActive = (m0 + wm) < jb.Mtot;
  unsigned short* ep = eplds[wave];
  if (waveActive) {
#pragma unroll
    for (int mf = 0; mf < 4; mf++)
#pragma unroll
      for (int nf = 0; nf < 4; nf++) {
        unsigned int u0 = (unsigned int)f2bf(acc[mf][nf][0]) | ((unsigned int)f2bf(acc[mf][nf][1]) << 16);
        unsigned int u1 = (unsigned int)f2bf(acc[mf][nf][2]) | ((unsigned int)f2bf(acc[mf][nf][3]) << 16);
        int base = (nf * 16 + l15) * 80 + mf * 16 + kg * 4;
        *reinterpret_cast<uint2v*>(ep + base) = (uint2v){u0, u1};
      }
  }
  __syncthreads();
  if (waveActive) {
    int cg = lane & 7, pg = lane >> 3;
    int coutBase = m0 + wm + cg * 8;
#pragma unroll
    for (int pi = 0; pi < 8; pi++) {
      int pixL = pi * 8 + pg;
      short8 row = *(const short8*)(ep + pixL * 80 + cg * 8);
      long ngl = blockIdx.x * 128 + wn + pixL;
      *(short8*)(jb.out + ngl * jb.outStride + coutBase) = row;
    }
  }
}

// ---------------- pointwise kernels (ch-minor threads, all coalesced) --------
__global__ void gates1_kernel(const unsigned short* __restrict__ xc,
                              const unsigned short* __restrict__ hc,
                              const unsigned short* __restrict__ mc,
                              float* __restrict__ cSt, float* __restrict__ mSt,
                              unsigned short* __restrict__ mP,
                              unsigned short* __restrict__ memP) {
  int tid = blockIdx.x * 256 + threadIdx.x;  // 64*16384
  int ch = tid & 63, n = tid >> 6;
  long xb = (long)n * 448, hb = (long)n * 256, mb = (long)n * 192;
  float i_x = bf2f(xc[xb + ch]);
  float f_x = bf2f(xc[xb + 64 + ch]);
  float g_x = bf2f(xc[xb + 128 + ch]);
  float ipx = bf2f(xc[xb + 192 + ch]);
  float fpx = bf2f(xc[xb + 256 + ch]);
  float gpx = bf2f(xc[xb + 320 + ch]);
  float i_h = bf2f(hc[hb + ch]);
  float f_h = bf2f(hc[hb + 64 + ch]);
  float g_h = bf2f(hc[hb + 128 + ch]);
  float i_m = bf2f(mc[mb + ch]);
  float f_m = bf2f(mc[mb + 64 + ch]);
  float g_m = bf2f(mc[mb + 128 + ch]);
  float it = sigm(i_x + i_h);
  float ft = sigm(f_x + f_h + 1.0f);
  float gt = tanhf(g_x + g_h);
  float cn = ft * cSt[tid] + it * gt;
  float itp = sigm(ipx + i_m);
  float ftp = sigm(fpx + f_m + 1.0f);
  float gtp = tanhf(gpx + g_m);
  float mn = ftp * mSt[tid] + itp * gtp;
  cSt[tid] = cn;
  mSt[tid] = mn;
  int bb = n >> 10, yy = (n >> 5) & 31, xx = n & 31;
  long p36 = bb * 1296 + (yy + 2) * 36 + (xx + 2);
  mP[p36 * 64 + ch] = f2bf(mn);
  memP[p36 * 128 + ch] = f2bf(cn);
  memP[p36 * 128 + 64 + ch] = f2bf(mn);
}

__global__ void gates2_kernel(const unsigned short* __restrict__ xc,
                              const unsigned short* __restrict__ hc,
                              const unsigned short* __restrict__ woP,
                              const unsigned short* __restrict__ ll,
                              unsigned short* __restrict__ hP) {
  int tid = blockIdx.x * 256 + threadIdx.x;  // 64*16384
  int ch = tid & 63, n = tid >> 6;
  float osum = 0.f;
#pragma unroll
  for (int c = 0; c < SPLITWO; c++)
    osum += bf2f(woP[(long)c * NPIX * 64 + (long)n * 64 + ch]);
  float opre = bf2f(xc[(long)n * 448 + 384 + ch]) +
               bf2f(hc[(long)n * 256 + 192 + ch]) + osum;
  float h = sigm(opre) * tanhf(bf2f(ll[(long)n * 64 + ch]));
  int bb = n >> 10, yy = (n >> 5) & 31, xx = n & 31;
  long p36 = bb * 1296 + (yy + 2) * 36 + (xx + 2);
  hP[p36 * 64 + ch] = f2bf(h);
}

__global__ void net_kernel(const float* __restrict__ frames,
                           const float* __restrict__ mask_true,
                           const float* __restrict__ xgen,
                           unsigned short* __restrict__ netP, int tstep) {
  int n = blockIdx.x * 256 + threadIdx.x;  // 16384 interior pixels
  int bb = n >> 10, yx = n & 1023;
  unsigned short vals[16];
#pragma unroll
  for (int c = 0; c < 16; c++) {
    float fr = frames[((long)(bb * 20 + tstep) * 16 + c) * 1024 + yx];
    float v;
    if (tstep < 10) {
      v = fr;
    } else {
      float mk = mask_true[((long)(bb * 9 + (tstep - 10)) * 16 + c) * 1024 + yx];
      v = mk * fr + (1.0f - mk) * xgen[(long)c * NPIX + n];
    }
    vals[c] = f2bf(v);
  }
  int yy = yx >> 5, xx = yx & 31;
  long p36 = bb * 1296 + (yy + 2) * 36 + (xx + 2);
  uint4v w0, w1;
#pragma unroll
  for (int j = 0; j < 4; j++) {
    w0[j] = (unsigned int)vals[2 * j] | ((unsigned int)vals[2 * j + 1] << 16);
    w1[j] = (unsigned int)vals[8 + 2 * j] | ((unsigned int)vals[8 + 2 * j + 1] << 16);
  }
  *reinterpret_cast<uint4v*>(netP + p36 * 16) = w0;
  *reinterpret_cast<uint4v*>(netP + p36 * 16 + 8) = w1;
}

__global__ void xgen_kernel(const unsigned short* __restrict__ hP3,
                            const float* __restrict__ Wlast,
                            float* __restrict__ xgen, float* __restrict__ out,
                            int tstep) {
  int n = blockIdx.x * 256 + threadIdx.x;  // 16384
  int bb = n >> 10, yx = n & 1023;
  int yy = yx >> 5, xx = yx & 31;
  long p36 = bb * 1296 + (yy + 2) * 36 + (xx + 2);
  const unsigned short* hp = hP3 + p36 * 64;
  float hv[64];
#pragma unroll
  for (int g = 0; g < 8; g++) {
    short8 v = *(const short8*)(hp + g * 8);
#pragma unroll
    for (int j = 0; j < 8; j++) hv[g * 8 + j] = bf2f((unsigned short)v[j]);
  }
#pragma unroll
  for (int co = 0; co < 16; co++) {
    float s = 0.f;
#pragma unroll
    for (int ci = 0; ci < 64; ci++) s += Wlast[co * 64 + ci] * hv[ci];
    xgen[(long)co * NPIX + n] = s;
    out[((long)(bb * TSTEPS + tstep) * 16 + co) * 1024 + yx] = s;
  }
}

// ---------------- host ----------------
extern "C" void kernel_launch(void* const* d_in, const int* in_sizes, int n_in,
                              void* d_out, int out_size, void* d_ws, size_t ws_size,
                              hipStream_t stream) {
  (void)in_sizes; (void)n_in; (void)out_size; (void)ws_size;
  const float* frames    = (const float*)d_in[0];
  const float* mask_true = (const float*)d_in[1];
  const float* Wx0       = (const float*)d_in[2];
  const float* Wxr       = (const float*)d_in[3];
  const float* Wh        = (const float*)d_in[4];
  const float* Wm        = (const float*)d_in[5];
  const float* Wo        = (const float*)d_in[6];
  const float* Wl        = (const float*)d_in[7];
  const float* Wlast     = (const float*)d_in[8];
  float* out = (float*)d_out;

  char* ws = (char*)d_ws;
  size_t cur = 0;
  auto alloc = [&](size_t bytes) -> char* {
    cur = (cur + 255) & ~(size_t)255;
    char* p = ws + cur;
    cur += bytes;
    return p;
  };

  // ---- zero-init region (padded ch-last activations + recurrent state) ----
  unsigned short* netP = (unsigned short*)alloc((size_t)PIXP * 16 * 2);
  unsigned short* hP[4];
  for (int l = 0; l < 4; l++) hP[l] = (unsigned short*)alloc((size_t)PIXP * 64 * 2);
  unsigned short* mP   = (unsigned short*)alloc((size_t)PIXP * 64 * 2);
  unsigned short* memP = (unsigned short*)alloc((size_t)PIXP * 128 * 2);
  float* cSt   = (float*)alloc((size_t)4 * NPIX * 64 * 4);
  float* mSt   = (float*)alloc((size_t)NPIX * 64 * 4);
  float* xgenB = (float*)alloc((size_t)16 * NPIX * 4);
  size_t zeroEnd = cur;

  // ---- packed weights (bf16, k-order = tap*Cin+ci) ----
  unsigned short* WxP0 = (unsigned short*)alloc((size_t)448 * 416 * 2);       // 26 taps x 16
  unsigned short* WxrP = (unsigned short*)alloc((size_t)3 * 448 * 1600 * 2);  // 25 x 64
  unsigned short* WhP  = (unsigned short*)alloc((size_t)4 * 256 * 1600 * 2);
  unsigned short* WmP  = (unsigned short*)alloc((size_t)4 * 192 * 1600 * 2);
  unsigned short* WoP  = (unsigned short*)alloc((size_t)4 * 64 * 3200 * 2);   // 25 x 128
  unsigned short* WlBF = (unsigned short*)alloc((size_t)4 * 64 * 128 * 2);    // 1x1: k=ci

  // ---- conv output buffers (bf16, ch-last) ----
  unsigned short* xcB = (unsigned short*)alloc((size_t)NPIX * 448 * 2);
  unsigned short* hcB = (unsigned short*)alloc((size_t)NPIX * 256 * 2);
  unsigned short* mcB = (unsigned short*)alloc((size_t)NPIX * 192 * 2);
  unsigned short* llB = (unsigned short*)alloc((size_t)NPIX * 64 * 2);
  unsigned short* woP = (unsigned short*)alloc((size_t)SPLITWO * NPIX * 64 * 2);

  // ---- setup ----
  zero_ws_kernel<<<1024, 256, 0, stream>>>((uint4v*)ws, (long)(zeroEnd / 16));
  {
    int n;
    n = 448 * 26 * 16;   pack_w_kernel<<<(n + 255) / 256, 256, 0, stream>>>(Wx0, WxP0, 448, 26, 16);
    n = 1344 * 25 * 64;  pack_w_kernel<<<(n + 255) / 256, 256, 0, stream>>>(Wxr, WxrP, 1344, 25, 64);
    n = 1024 * 25 * 64;  pack_w_kernel<<<(n + 255) / 256, 256, 0, stream>>>(Wh, WhP, 1024, 25, 64);
    n = 768 * 25 * 64;   pack_w_kernel<<<(n + 255) / 256, 256, 0, stream>>>(Wm, WmP, 768, 25, 64);
    n = 256 * 25 * 128;  pack_w_kernel<<<(n + 255) / 256, 256, 0, stream>>>(Wo, WoP, 256, 25, 128);
    n = 4 * 64 * 128;    cvt_bf16_kernel<<<(n + 255) / 256, 256, 0, stream>>>(Wl, WlBF, n);
  }

  // ---- time loop ----
  for (int t = 0; t < TSTEPS; t++) {
    net_kernel<<<64, 256, 0, stream>>>(frames, mask_true, xgenB, netP, t);

    for (int l = 0; l < 4; l++) {
      // xc (net l=0 / h[l-1] else) + mc (m) + hc (h[l] old value — hP[l] is
      // only overwritten by gates2(l) below). M-tiles of 128 -> y = 4+2+2.
      JobSet ca{};
      ca.njobs = 3;
      if (l == 0) ca.jobs[0] = Job{ WxP0, netP, xcB, 448, 416, 416, 0, 4, 0, 0, 448 };
      else        ca.jobs[0] = Job{ WxrP + (size_t)(l - 1) * 448 * 1600, hP[l - 1], xcB, 448, 1600, 1600, 0, 6, 0, 0, 448 };
      ca.jobs[1] = Job{ WmP + (size_t)l * 192 * 1600, mP, mcB, 192, 1600, 1600, 0, 6, 4, 0, 192 };
      ca.jobs[2] = Job{ WhP + (size_t)l * 256 * 1600, hP[l], hcB, 256, 1600, 1600, 0, 6, 6, 0, 256 };
      conv_gemm<<<dim3(128, 8), 256, 0, stream>>>(ca);

      gates1_kernel<<<4096, 256, 0, stream>>>(xcB, hcB, mcB,
                                              cSt + (size_t)l * NPIX * 64, mSt, mP, memP);

      // wo (5x5 over mem, split-K x4, bf16 partials) + wl (1x1 over mem)
      JobSet cb{};
      cb.njobs = SPLITWO + 1;
      for (int c = 0; c < SPLITWO; c++)
        cb.jobs[c] = Job{ WoP + (size_t)l * 64 * 3200 + 800 * c, memP,
                          woP + (size_t)c * NPIX * 64, 64, 800, 3200, 800 * c, 7, c, 0, 64 };
      cb.jobs[SPLITWO] = Job{ WlBF + (size_t)l * 64 * 128, memP, llB, 64, 128, 128, 0, 7, SPLITWO, 74, 64 };
      conv_gemm<<<dim3(128, SPLITWO + 1), 256, 0, stream>>>(cb);

      gates2_kernel<<<4096, 256, 0, stream>>>(xcB, hcB, woP, llB, hP[l]);
    }

    xgen_kernel<<<64, 256, 0, stream>>>(hP[3], Wlast, xgenB, out, t);
  }
}

// Round 10
// 11588.637 us; speedup vs baseline: 1.4687x; 1.4687x over previous
//
#include <hip/hip_runtime.h>

#define NPIX 16384      // B*H*W interior pixels
#define PIXP 20736      // BATCH*36*36 padded pixels
#define TSTEPS 19
#define TILE_PX 432     // 12 rows x 36 cols staged per block
#define LDSB 55296      // 432 * 128 bytes (Cin=64 case, max)

typedef __attribute__((ext_vector_type(8))) short short8;
typedef __attribute__((ext_vector_type(4))) float f32x4;
typedef __attribute__((ext_vector_type(4))) unsigned int uint4v;
typedef __attribute__((ext_vector_type(2))) unsigned int uint2v;

__device__ __forceinline__ float bf2f(unsigned short u) {
  union { unsigned int i; float f; } v; v.i = ((unsigned int)u) << 16; return v.f;
}
__device__ __forceinline__ unsigned short f2bf(float f) {
  union { float f; unsigned int i; } v; v.f = f;
  unsigned int r = v.i + 0x7FFFu + ((v.i >> 16) & 1u);
  return (unsigned short)(r >> 16);
}
__device__ __forceinline__ unsigned int pk2(float a, float b) {
  return (unsigned int)f2bf(a) | ((unsigned int)f2bf(b) << 16);
}
__device__ __forceinline__ float sigm(float x) { return 1.0f / (1.0f + __expf(-x)); }

// Conv job. K-order (tap, ci), k = tap*Cin + ci. Weights packed fragment-native:
// [mtile][ks][mfrag8][lane64][8] so an A-frag load is 64 lanes x 16B contiguous.
// Input staged to LDS as [432 px][Cin] with XOR bank swizzle.
struct Job {
  const unsigned short* W;
  const unsigned short* inP;   // padded ch-last base
  unsigned short* out;         // ch-last [NPIX][outStrideE]
  int outStrideE;
  int NKS;                     // K/32
  int lc;                      // log2(Cin of tile): 4 or 6
  int srcCiB;                  // bytes per pixel in global inP (32/128/256)
  int srcCiOff;                // byte offset within pixel (wo half: h*128)
  int yBase;
  int Mtot;                    // valid rows (multiple of 64)
  int colOff;                  // output column offset (wo half: h*64)
};
struct JobSet { Job jobs[4]; int njobs; };

// ---------------- setup kernels ----------------
__global__ void zero_ws_kernel(uint4v* p, long n16) {
  long i = (long)blockIdx.x * blockDim.x + threadIdx.x;
  long stride = (long)gridDim.x * blockDim.x;
  uint4v z = {0u, 0u, 0u, 0u};
  for (; i < n16; i += stride) p[i] = z;
}

// OIHW f32 -> fragment-native bf16 [MT][NKS][mfg8][lane64][8]
__global__ void pack_w_kernel(const float* __restrict__ s, unsigned short* __restrict__ d,
                              int Mtot, int MT, int NKS, int lc, int srcCin, int ciOff) {
  int i = blockIdx.x * 256 + threadIdx.x;
  int per = NKS * 4096;
  if (i >= MT * per) return;
  int mt = i / per, r = i - mt * per;
  int ks = r >> 12, q = r & 4095;
  int mfg = q >> 9, lane = (q >> 3) & 63, j = q & 7;
  int m = mt * 128 + mfg * 16 + (lane & 15);
  int k = ks * 32 + (lane >> 4) * 8 + j;
  int tap = k >> lc, ci = k & ((1 << lc) - 1);
  float v = (m < Mtot && tap < 25) ? s[((long)m * srcCin + ciOff + ci) * 25 + tap] : 0.0f;
  d[i] = f2bf(v);
}

// ---------------- conv implicit-GEMM: LDS im2col tile, frag-native weights ---
// Block 128m x 256px (8 rows of one image). 4 waves = (2 m-halves) x (2 px-halves);
// wave = 64m x 128px. K-step 32: 4 A dwordx4 (coalesced) + 8 swizzled ds_read_b128
// + 32 MFMA. Tile staged once; NO barriers in the K-loop.
__global__ __launch_bounds__(256, 2) void conv_gemm(JobSet js) {
  __shared__ __align__(16) unsigned char lds[LDSB];

  int by = blockIdx.y;
  Job jb = js.jobs[0];
#pragma unroll
  for (int q = 1; q < 4; q++)
    if (q < js.njobs && by >= js.jobs[q].yBase) jb = js.jobs[q];
  int mt = by - jb.yBase;

  int t = threadIdx.x;
  int lane = t & 63, wave = t >> 6;
  int wm = wave >> 1, wn = wave & 1;
  int l15 = lane & 15, kg = lane >> 4;
  int s = jb.lc + 1;                       // byte shift: px -> byte
  int tileCiB = 2 << jb.lc;
  int tileBytes = TILE_PX * tileCiB;
  int cinMask = (1 << jb.lc) - 1;

  int bx = blockIdx.x;
  int bb = bx >> 2, Y0 = (bx & 3) * 8;     // 8 output rows per block
  long pxStartByte = ((long)bb * 1296 + Y0 * 36) * jb.srcCiB;

  // ---- stage input tile (12 rows x 36 cols x Cin), swizzled ----
  {
    const char* ip = (const char*)jb.inP;
#pragma unroll
    for (int g = 0; g < 14; g++) {
      int fb = (g * 256 + t) * 16;
      if (fb < tileBytes) {
        int px = fb >> s;
        int cib = fb & (tileCiB - 1);
        uint4v v = *(const uint4v*)(ip + pxStartByte + (long)px * jb.srcCiB + jb.srcCiOff + cib);
        *(uint4v*)(lds + (fb ^ ((px & 7) << 4))) = v;
      }
    }
  }
  __syncthreads();

  // B pixel indices (tile-local, no tap): wave pixel p = wn*128 + nf*16 + l15
  int pxB[8];
#pragma unroll
  for (int nf = 0; nf < 8; nf++) {
    int p = wn * 128 + nf * 16 + l15;
    pxB[nf] = (p >> 5) * 36 + (p & 31);
  }

  const char* Wp = (const char*)(jb.W + (long)mt * jb.NKS * 4096);

  f32x4 acc[4][8];
#pragma unroll
  for (int mf = 0; mf < 4; mf++)
#pragma unroll
    for (int nf = 0; nf < 8; nf++) acc[mf][nf] = (f32x4){0.f, 0.f, 0.f, 0.f};

  short8 aA[4], aB[4], bA[8], bB[8];

  auto loadA = [&](short8* a, int ks) {
    const char* base = Wp + (long)(ks * 8 + wm * 4) * 1024 + lane * 16;
#pragma unroll
    for (int mf = 0; mf < 4; mf++)
      a[mf] = *(const short8*)(base + mf * 1024);
  };
  auto loadB = [&](short8* b, int ks) {
    int kl = ks * 32 + kg * 8;
    int tap = kl >> jb.lc; if (tap > 24) tap = 24;   // Wx0 zero-pad taps
    int ci0b = (kl & cinMask) * 2;
    int dy = (tap * 13) >> 6;
    int tOff = dy * 36 + (tap - dy * 5);
#pragma unroll
    for (int nf = 0; nf < 8; nf++) {
      int px = pxB[nf] + tOff;
      int byte = (px << s) + ci0b;
      byte ^= ((px & 7) << 4);
      b[nf] = *(const short8*)(lds + byte);
    }
  };
  auto mm = [&](short8* a, short8* b) {
#pragma unroll
    for (int mf = 0; mf < 4; mf++)
#pragma unroll
      for (int nf = 0; nf < 8; nf++)
        acc[mf][nf] = __builtin_amdgcn_mfma_f32_16x16x32_bf16(a[mf], b[nf], acc[mf][nf], 0, 0, 0);
  };

  int NKS = jb.NKS;
  loadA(aA, 0); loadB(bA, 0);
  int ks = 0;
  while (true) {
    if (ks + 1 < NKS) { loadA(aB, ks + 1); loadB(bB, ks + 1); }
    mm(aA, bA);
    ks++; if (ks >= NKS) break;
    if (ks + 1 < NKS) { loadA(aA, ks + 1); loadB(bA, ks + 1); }
    mm(aB, bB);
    ks++; if (ks >= NKS) break;
  }

  // ---- epilogue: per-wave LDS transpose (2 px-passes of 64) -> ch-last ----
  __syncthreads();    // all waves done reading the tile
  int mBase = mt * 128 + wm * 64;
  if (mBase < jb.Mtot) {
    unsigned char* wl = lds + wave * 13824;
#pragma unroll
    for (int pass = 0; pass < 2; pass++) {
#pragma unroll
      for (int mf = 0; mf < 4; mf++)
#pragma unroll
        for (int nfl = 0; nfl < 4; nfl++) {
          int nf = pass * 4 + nfl;
          int pxl = nfl * 16 + l15;
          int mo = mf * 32 + kg * 8;
          int wb = (pxl * 128 + mo) ^ ((pxl & 7) << 4);
          uint2v u = { pk2(acc[mf][nf][0], acc[mf][nf][1]),
                       pk2(acc[mf][nf][2], acc[mf][nf][3]) };
          *(uint2v*)(wl + wb) = u;
        }
      // wave-local: compiler inserts lgkmcnt before dependent reads
#pragma unroll
      for (int pi = 0; pi < 8; pi++) {
        int pxl = pi * 8 + (lane >> 3);
        int mo = (lane & 7) * 16;
        int rb = (pxl * 128 + mo) ^ ((pxl & 7) << 4);
        short8 row = *(const short8*)(wl + rb);
        long pxG = (long)bx * 256 + wn * 128 + pass * 64 + pxl;
        *(short8*)(jb.out + pxG * jb.outStrideE + jb.colOff + mBase + (lane & 7) * 8) = row;
      }
      if (pass == 0) { /* distinct LDS bytes per pass? pass1 reuses region; in-wave ordering ok */ }
    }
  }
}

// ---------------- pointwise kernels (ch-minor threads, coalesced) ------------
__global__ void gates1_kernel(const unsigned short* __restrict__ xc,
                              const unsigned short* __restrict__ hc,
                              const unsigned short* __restrict__ mc,
                              float* __restrict__ cSt, float* __restrict__ mSt,
                              unsigned short* __restrict__ mP,
                              unsigned short* __restrict__ memP) {
  int tid = blockIdx.x * 256 + threadIdx.x;  // 64*16384
  int ch = tid & 63, n = tid >> 6;
  long xb = (long)n * 448, hb = (long)n * 256, mb = (long)n * 192;
  float i_x = bf2f(xc[xb + ch]);
  float f_x = bf2f(xc[xb + 64 + ch]);
  float g_x = bf2f(xc[xb + 128 + ch]);
  float ipx = bf2f(xc[xb + 192 + ch]);
  float fpx = bf2f(xc[xb + 256 + ch]);
  float gpx = bf2f(xc[xb + 320 + ch]);
  float i_h = bf2f(hc[hb + ch]);
  float f_h = bf2f(hc[hb + 64 + ch]);
  float g_h = bf2f(hc[hb + 128 + ch]);
  float i_m = bf2f(mc[mb + ch]);
  float f_m = bf2f(mc[mb + 64 + ch]);
  float g_m = bf2f(mc[mb + 128 + ch]);
  float it = sigm(i_x + i_h);
  float ft = sigm(f_x + f_h + 1.0f);
  float gt = tanhf(g_x + g_h);
  float cn = ft * cSt[tid] + it * gt;
  float itp = sigm(ipx + i_m);
  float ftp = sigm(fpx + f_m + 1.0f);
  float gtp = tanhf(gpx + g_m);
  float mn = ftp * mSt[tid] + itp * gtp;
  cSt[tid] = cn;
  mSt[tid] = mn;
  int bb = n >> 10, yy = (n >> 5) & 31, xx = n & 31;
  long p36 = bb * 1296 + (yy + 2) * 36 + (xx + 2);
  mP[p36 * 64 + ch] = f2bf(mn);
  memP[p36 * 128 + ch] = f2bf(cn);
  memP[p36 * 128 + 64 + ch] = f2bf(mn);
}

// gates2 now also computes the wl 1x1 conv (K=128 dot over mem) in f32.
__global__ void gates2_kernel(const unsigned short* __restrict__ xc,
                              const unsigned short* __restrict__ hc,
                              const unsigned short* __restrict__ woB,
                              const unsigned short* __restrict__ memP,
                              const float* __restrict__ Wl,   // [64][128] f32
                              unsigned short* __restrict__ hP) {
  int tid = blockIdx.x * 256 + threadIdx.x;  // 64*16384
  int ch = tid & 63, n = tid >> 6;
  float osum = bf2f(woB[(long)n * 128 + ch]) + bf2f(woB[(long)n * 128 + 64 + ch]);
  int bb = n >> 10, yy = (n >> 5) & 31, xx = n & 31;
  long p36 = bb * 1296 + (yy + 2) * 36 + (xx + 2);
  const unsigned short* mp = memP + p36 * 128;
  const float* wl = Wl + ch * 128;
  float ll = 0.f;
#pragma unroll
  for (int g = 0; g < 16; g++) {
    short8 v = *(const short8*)(mp + g * 8);
#pragma unroll
    for (int j = 0; j < 8; j++) ll += wl[g * 8 + j] * bf2f((unsigned short)v[j]);
  }
  float opre = bf2f(xc[(long)n * 448 + 384 + ch]) +
               bf2f(hc[(long)n * 256 + 192 + ch]) + osum;
  float h = sigm(opre) * tanhf(ll);
  hP[p36 * 64 + ch] = f2bf(h);
}

__global__ void net_kernel(const float* __restrict__ frames,
                           const float* __restrict__ mask_true,
                           const float* __restrict__ xgen,
                           unsigned short* __restrict__ netP, int tstep) {
  int n = blockIdx.x * 256 + threadIdx.x;  // 16384 interior pixels
  int bb = n >> 10, yx = n & 1023;
  unsigned short vals[16];
#pragma unroll
  for (int c = 0; c < 16; c++) {
    float fr = frames[((long)(bb * 20 + tstep) * 16 + c) * 1024 + yx];
    float v;
    if (tstep < 10) {
      v = fr;
    } else {
      float mk = mask_true[((long)(bb * 9 + (tstep - 10)) * 16 + c) * 1024 + yx];
      v = mk * fr + (1.0f - mk) * xgen[(long)c * NPIX + n];
    }
    vals[c] = f2bf(v);
  }
  int yy = yx >> 5, xx = yx & 31;
  long p36 = bb * 1296 + (yy + 2) * 36 + (xx + 2);
  uint4v w0, w1;
#pragma unroll
  for (int j = 0; j < 4; j++) {
    w0[j] = (unsigned int)vals[2 * j] | ((unsigned int)vals[2 * j + 1] << 16);
    w1[j] = (unsigned int)vals[8 + 2 * j] | ((unsigned int)vals[8 + 2 * j + 1] << 16);
  }
  *reinterpret_cast<uint4v*>(netP + p36 * 16) = w0;
  *reinterpret_cast<uint4v*>(netP + p36 * 16 + 8) = w1;
}

__global__ void xgen_kernel(const unsigned short* __restrict__ hP3,
                            const float* __restrict__ Wlast,
                            float* __restrict__ xgen, float* __restrict__ out,
                            int tstep) {
  int n = blockIdx.x * 256 + threadIdx.x;  // 16384
  int bb = n >> 10, yx = n & 1023;
  int yy = yx >> 5, xx = yx & 31;
  long p36 = bb * 1296 + (yy + 2) * 36 + (xx + 2);
  const unsigned short* hp = hP3 + p36 * 64;
  float hv[64];
#pragma unroll
  for (int g = 0; g < 8; g++) {
    short8 v = *(const short8*)(hp + g * 8);
#pragma unroll
    for (int j = 0; j < 8; j++) hv[g * 8 + j] = bf2f((unsigned short)v[j]);
  }
#pragma unroll
  for (int co = 0; co < 16; co++) {
    float s = 0.f;
#pragma unroll
    for (int ci = 0; ci < 64; ci++) s += Wlast[co * 64 + ci] * hv[ci];
    xgen[(long)co * NPIX + n] = s;
    out[((long)(bb * TSTEPS + tstep) * 16 + co) * 1024 + yx] = s;
  }
}

// ---------------- host ----------------
extern "C" void kernel_launch(void* const* d_in, const int* in_sizes, int n_in,
                              void* d_out, int out_size, void* d_ws, size_t ws_size,
                              hipStream_t stream) {
  (void)in_sizes; (void)n_in; (void)out_size; (void)ws_size;
  const float* frames    = (const float*)d_in[0];
  const float* mask_true = (const float*)d_in[1];
  const float* Wx0       = (const float*)d_in[2];
  const float* Wxr       = (const float*)d_in[3];
  const float* Wh        = (const float*)d_in[4];
  const float* Wm        = (const float*)d_in[5];
  const float* Wo        = (const float*)d_in[6];
  const float* Wl        = (const float*)d_in[7];
  const float* Wlast     = (const float*)d_in[8];
  float* out = (float*)d_out;

  char* ws = (char*)d_ws;
  size_t cur = 0;
  auto alloc = [&](size_t bytes) -> char* {
    cur = (cur + 255) & ~(size_t)255;
    char* p = ws + cur;
    cur += bytes;
    return p;
  };

  // ---- zero-init region (padded ch-last activations + recurrent state) ----
  unsigned short* netP = (unsigned short*)alloc((size_t)PIXP * 16 * 2);
  unsigned short* hP[4];
  for (int l = 0; l < 4; l++) hP[l] = (unsigned short*)alloc((size_t)PIXP * 64 * 2);
  unsigned short* mP   = (unsigned short*)alloc((size_t)PIXP * 64 * 2);
  unsigned short* memP = (unsigned short*)alloc((size_t)PIXP * 128 * 2);
  float* cSt   = (float*)alloc((size_t)4 * NPIX * 64 * 4);
  float* mSt   = (float*)alloc((size_t)NPIX * 64 * 4);
  float* xgenB = (float*)alloc((size_t)16 * NPIX * 4);
  size_t zeroEnd = cur;

  // ---- fragment-native packed weights (bf16) ----
  unsigned short* WxP0 = (unsigned short*)alloc((size_t)4 * 13 * 4096 * 2);
  unsigned short* WxrP = (unsigned short*)alloc((size_t)3 * 4 * 50 * 4096 * 2);
  unsigned short* WhP  = (unsigned short*)alloc((size_t)4 * 2 * 50 * 4096 * 2);
  unsigned short* WmP  = (unsigned short*)alloc((size_t)4 * 2 * 50 * 4096 * 2);
  unsigned short* WoP  = (unsigned short*)alloc((size_t)8 * 1 * 50 * 4096 * 2);

  // ---- conv output buffers (bf16, ch-last) ----
  unsigned short* xcB = (unsigned short*)alloc((size_t)NPIX * 448 * 2);
  unsigned short* hcB = (unsigned short*)alloc((size_t)NPIX * 256 * 2);
  unsigned short* mcB = (unsigned short*)alloc((size_t)NPIX * 192 * 2);
  unsigned short* woB = (unsigned short*)alloc((size_t)NPIX * 128 * 2);

  // ---- setup ----
  zero_ws_kernel<<<1024, 256, 0, stream>>>((uint4v*)ws, (long)(zeroEnd / 16));
  {
    int n;
    n = 4 * 13 * 4096;
    pack_w_kernel<<<(n + 255) / 256, 256, 0, stream>>>(Wx0, WxP0, 448, 4, 13, 4, 16, 0);
    for (int l = 0; l < 3; l++) {
      n = 4 * 50 * 4096;
      pack_w_kernel<<<(n + 255) / 256, 256, 0, stream>>>(
          Wxr + (size_t)l * 448 * 64 * 25, WxrP + (size_t)l * 4 * 50 * 4096, 448, 4, 50, 6, 64, 0);
    }
    for (int l = 0; l < 4; l++) {
      n = 2 * 50 * 4096;
      pack_w_kernel<<<(n + 255) / 256, 256, 0, stream>>>(
          Wh + (size_t)l * 256 * 64 * 25, WhP + (size_t)l * 2 * 50 * 4096, 256, 2, 50, 6, 64, 0);
      pack_w_kernel<<<(n + 255) / 256, 256, 0, stream>>>(
          Wm + (size_t)l * 192 * 64 * 25, WmP + (size_t)l * 2 * 50 * 4096, 192, 2, 50, 6, 64, 0);
      n = 1 * 50 * 4096;
      for (int h = 0; h < 2; h++)
        pack_w_kernel<<<(n + 255) / 256, 256, 0, stream>>>(
            Wo + (size_t)l * 64 * 128 * 25, WoP + (size_t)(l * 2 + h) * 50 * 4096, 64, 1, 50, 6, 128, h * 64);
    }
  }

  // ---- time loop ----
  for (int t = 0; t < TSTEPS; t++) {
    net_kernel<<<64, 256, 0, stream>>>(frames, mask_true, xgenB, netP, t);

    for (int l = 0; l < 4; l++) {
      // xc (net l=0 / h[l-1] else) + mc (m) + hc (h[l] old value; hP[l] is
      // only overwritten by gates2(l) below). y tiles: 4 + 2 + 2.
      JobSet ca{};
      ca.njobs = 3;
      if (l == 0) ca.jobs[0] = Job{ WxP0, netP, xcB, 448, 13, 4, 32, 0, 0, 448, 0 };
      else        ca.jobs[0] = Job{ WxrP + (size_t)(l - 1) * 4 * 50 * 4096, hP[l - 1], xcB, 448, 50, 6, 128, 0, 0, 448, 0 };
      ca.jobs[1] = Job{ WmP + (size_t)l * 2 * 50 * 4096, mP, mcB, 192, 50, 6, 128, 0, 4, 192, 0 };
      ca.jobs[2] = Job{ WhP + (size_t)l * 2 * 50 * 4096, hP[l], hcB, 256, 50, 6, 128, 0, 6, 256, 0 };
      conv_gemm<<<dim3(64, 8), 256, 0, stream>>>(ca);

      gates1_kernel<<<4096, 256, 0, stream>>>(xcB, hcB, mcB,
                                              cSt + (size_t)l * NPIX * 64, mSt, mP, memP);

      // wo (5x5 over mem = c-half + m-half convs, summed in gates2)
      JobSet cb{};
      cb.njobs = 2;
      for (int h = 0; h < 2; h++)
        cb.jobs[h] = Job{ WoP + (size_t)(l * 2 + h) * 50 * 4096, memP, woB,
                          128, 50, 6, 256, h * 128, h, 64, h * 64 };
      conv_gemm<<<dim3(64, 2), 256, 0, stream>>>(cb);

      gates2_kernel<<<4096, 256, 0, stream>>>(xcB, hcB, woB, memP,
                                              Wl + (size_t)l * 64 * 128, hP[l]);
    }

    xgen_kernel<<<64, 256, 0, stream>>>(hP[3], Wlast, xgenB, out, t);
  }
}